// Round 2
// baseline (34147.510 us; speedup 1.0000x reference)
//
#include <hip/hip_runtime.h>
#include <stdint.h>

typedef unsigned int u32;
typedef unsigned long long u64;
typedef unsigned short u16;
typedef __attribute__((ext_vector_type(8))) short s8;
typedef __attribute__((ext_vector_type(4))) float f4;

#define NWG 256
#define TPB 512
#define NB 64      // batch
#define TT 400     // seq len
#define EE 300     // embed dim
#define HEN 512    // encoder hidden
#define HD 1024    // decoder hidden
#define VV 50000   // vocab
#define DEC 80     // decode steps
#define NTL 3125   // VV/16 n-tiles
#define LCAP 512   // rescue list capacity

struct P {
  const int* texts; const int* len; const float* emb;
  const float* ewih0; const float* ewhh0; const float* ebih0; const float* ebhh0;
  const float* ewih1; const float* ewhh1; const float* ebih1; const float* ebhh1;
  const float* dwih; const float* dwhh; const float* dbih; const float* dbhh;
  const float* outw; const float* outb;
  float* out;
  u16* owbf; float* xT; float* hTf; float* hTb; float* hTd; u16* hbf;
  u64* prt; int* tok; float* wn; float* hn2; u32* cnt;
};

__device__ __forceinline__ void gbar(u32* cnt) {
  __syncthreads();
  if (threadIdx.x == 0) {
    __builtin_amdgcn_fence(__ATOMIC_RELEASE, "agent");
    u32 t = __hip_atomic_fetch_add(cnt, 1u, __ATOMIC_RELAXED, __HIP_MEMORY_SCOPE_AGENT);
    u32 target = (t / NWG + 1u) * NWG;
    while (__hip_atomic_load(cnt, __ATOMIC_RELAXED, __HIP_MEMORY_SCOPE_AGENT) < target)
      __builtin_amdgcn_s_sleep(2);
    __builtin_amdgcn_fence(__ATOMIC_ACQUIRE, "agent");
  }
  __syncthreads();
}

__device__ __forceinline__ u32 fkey(float v) {
  u32 u = __float_as_uint(v);
  return (u & 0x80000000u) ? ~u : (u | 0x80000000u);
}
__device__ __forceinline__ u16 f2bf(float f) {   // RNE fp32->bf16
  u32 u = __float_as_uint(f);
  u32 r = u + 0x7FFFu + ((u >> 16) & 1u);
  return (u16)(r >> 16);
}
__device__ __forceinline__ float sigm(float x) { return 1.f / (1.f + expf(-x)); }

// One GRU time-step, 4 hidden cols per workgroup; lane = batch.
// h layouts k-major [k][NB]; 8 waves split (x:EL | h:HL) k-axis, combine in LDS.
__device__ __forceinline__ void gru_phase(
    const P& p, float* smf, int jjb, int EL, int HL,
    const float* xsrc, const int* tokp,
    const float* __restrict__ wih, const float* __restrict__ whh,
    const float* bih, const float* bhh,
    const float* __restrict__ hc, float* ho,
    int mask_t, const int* lenp, u16* hbf_out, float* hn2slot)
{
  const int tid = threadIdx.x, lane = tid & 63, wv = tid >> 6;
  const int KT = EL + HL;
  const int vs = (wv * KT) >> 3, ve = ((wv + 1) * KT) >> 3;
  float ar[4] = {0,0,0,0}, az[4] = {0,0,0,0}, ax[4] = {0,0,0,0}, ah[4] = {0,0,0,0};
  int xe = ve < EL ? ve : EL;
  if (vs < EL) {
    if (xsrc) {
      for (int k = vs; k < xe; k++) {
        float xv = xsrc[(size_t)k * NB + lane];
        #pragma unroll
        for (int j = 0; j < 4; j++) {
          int jj = jjb + j;
          ar[j] = fmaf(xv, wih[(size_t)jj * EL + k], ar[j]);
          az[j] = fmaf(xv, wih[(size_t)(HL + jj) * EL + k], az[j]);
          ax[j] = fmaf(xv, wih[(size_t)(2 * HL + jj) * EL + k], ax[j]);
        }
      }
    } else {
      const float* xr = p.emb + (size_t)tokp[lane] * EL;
      for (int k = vs; k < xe; k++) {
        float xv = xr[k];
        #pragma unroll
        for (int j = 0; j < 4; j++) {
          int jj = jjb + j;
          ar[j] = fmaf(xv, wih[(size_t)jj * EL + k], ar[j]);
          az[j] = fmaf(xv, wih[(size_t)(HL + jj) * EL + k], az[j]);
          ax[j] = fmaf(xv, wih[(size_t)(2 * HL + jj) * EL + k], ax[j]);
        }
      }
    }
  }
  int hs = vs - EL; if (hs < 0) hs = 0;
  int he = ve - EL;
  for (int k = hs; k < he; k++) {
    float hv = hc[(size_t)k * NB + lane];
    #pragma unroll
    for (int j = 0; j < 4; j++) {
      int jj = jjb + j;
      ar[j] = fmaf(hv, whh[(size_t)jj * HL + k], ar[j]);
      az[j] = fmaf(hv, whh[(size_t)(HL + jj) * HL + k], az[j]);
      ah[j] = fmaf(hv, whh[(size_t)(2 * HL + jj) * HL + k], ah[j]);
    }
  }
  #pragma unroll
  for (int j = 0; j < 4; j++) {
    smf[((wv * 16 + j * 4 + 0) * 64) + lane] = ar[j];
    smf[((wv * 16 + j * 4 + 1) * 64) + lane] = az[j];
    smf[((wv * 16 + j * 4 + 2) * 64) + lane] = ax[j];
    smf[((wv * 16 + j * 4 + 3) * 64) + lane] = ah[j];
  }
  float* hsq = smf + 8192;
  if (hn2slot && tid < 64) hsq[tid] = 0.f;
  __syncthreads();
  if (tid < 256) {
    int b = tid & 63, j = tid >> 6;
    int jj = jjb + j;
    float r = 0, z = 0, xn = 0, hn = 0;
    #pragma unroll
    for (int w = 0; w < 8; w++) {
      int base = ((w * 16 + j * 4) * 64) + b;
      r  += smf[base];
      z  += smf[base + 64];
      xn += smf[base + 128];
      hn += smf[base + 192];
    }
    r = sigm(r + bih[jj] + bhh[jj]);
    z = sigm(z + bih[HL + jj] + bhh[HL + jj]);
    float nn = tanhf(xn + bih[2 * HL + jj] + r * (hn + bhh[2 * HL + jj]));
    float hold = hc[(size_t)jj * NB + b];
    float hv = (1.f - z) * nn + z * hold;
    if (lenp && mask_t >= lenp[b]) hv = hold;
    ho[(size_t)jj * NB + b] = hv;
    if (hbf_out) hbf_out[(size_t)b * HD + jj] = f2bf(hv);
    if (hn2slot) atomicAdd(&hsq[b], hv * hv);
  }
  if (hn2slot) {           // wg-uniform branch: barrier is safe
    __syncthreads();
    if (tid < 64) atomicAdd(&hn2slot[tid], hsq[tid]);
  }
}

__global__ void __launch_bounds__(TPB, 2) seq2seq_kernel(P p) {
  __shared__ __align__(16) unsigned char smem[34816];
  const int wg = blockIdx.x, tid = threadIdx.x;
  const int lane = tid & 63, wv = tid >> 6;
  const int gtid = wg * TPB + tid;

  // ---------------- phase 0: one-time prep ----------------
  {
    // out_w -> bf16 copy + per-row L2 norm (for the certified rescue bound)
    int gwv = wg * 8 + wv;
    for (int v = gwv; v < VV; v += 2048) {
      const float* wr = p.outw + (size_t)v * HD + lane * 16;
      u16* dst = p.owbf + (size_t)v * HD + lane * 16;
      float sa = 0.f;
      u32 pk[8];
      #pragma unroll
      for (int q = 0; q < 4; q++) {
        float4 f = *(const float4*)(wr + q * 4);
        sa += f.x * f.x + f.y * f.y + f.z * f.z + f.w * f.w;
        pk[q * 2 + 0] = (u32)f2bf(f.x) | ((u32)f2bf(f.y) << 16);
        pk[q * 2 + 1] = (u32)f2bf(f.z) | ((u32)f2bf(f.w) << 16);
      }
      *(uint4*)(dst)     = make_uint4(pk[0], pk[1], pk[2], pk[3]);
      *(uint4*)(dst + 8) = make_uint4(pk[4], pk[5], pk[6], pk[7]);
      #pragma unroll
      for (int d = 1; d < 64; d <<= 1) sa += __shfl_xor(sa, d);
      if (lane == 0) p.wn[v] = sqrtf(sa);
    }
    // gather+transpose encoder inputs: xT[t][k][b] = emb[texts[b][t]][k]
    const long long tot = (long long)TT * NB * EE;
    for (long long i = gtid; i < tot; i += (long long)NWG * TPB) {
      int t = (int)(i / (NB * EE));
      int rr = (int)(i % (NB * EE));
      int b2 = rr / EE, k = rr % EE;
      float v = p.emb[(size_t)p.texts[b2 * TT + t] * EE + k];
      p.xT[((size_t)t * EE + k) * NB + b2] = v;
    }
  }
  gbar(p.cnt);

  // ---------------- phase 1: bidirectional encoder ----------------
  {
    const int dir = wg >> 7;           // wgs 0..127 fwd, 128..255 bwd
    const int jjb = (wg & 127) * 4;
    const float* wih = dir ? p.ewih1 : p.ewih0;
    const float* whh = dir ? p.ewhh1 : p.ewhh0;
    const float* bih = dir ? p.ebih1 : p.ebih0;
    const float* bhh = dir ? p.ebhh1 : p.ebhh0;
    float* hbase = dir ? p.hTb : p.hTf;
    float* smf = (float*)smem;
    for (int t = 0; t < TT; t++) {
      int te = dir ? (TT - 1 - t) : t;
      const float* hc = hbase + (size_t)(t & 1) * HEN * NB;
      float* ho = hbase + (size_t)((t + 1) & 1) * HEN * NB;
      gru_phase(p, smf, jjb, EE, HEN, p.xT + (size_t)te * EE * NB, nullptr,
                wih, whh, bih, bhh, hc, ho, te, p.len, nullptr, nullptr);
      gbar(p.cnt);
    }
  }

  // ---------------- phase 2: concat hidden, init tok ----------------
  {
    for (int i = gtid; i < HD * NB; i += NWG * TPB) {
      int k = i / NB, b2 = i % NB;
      float v = (k < HEN) ? p.hTf[(size_t)k * NB + b2] : p.hTb[(size_t)(k - HEN) * NB + b2];
      p.hTd[i] = v;
    }
    if (gtid < NB) p.tok[gtid] = 1;   // sos
  }
  gbar(p.cnt);

  // ---------------- phase 3: decoder ----------------
  for (int s = 0; s < DEC; s++) {
    const float* hc = p.hTd + (size_t)(s & 1) * HD * NB;
    float* ho = p.hTd + (size_t)((s + 1) & 1) * HD * NB;
    // 3a: GRU step (emits bf16 row-major h and per-batch ||h||^2)
    gru_phase(p, (float*)smem, wg * 4, EE, HD, nullptr, p.tok,
              p.dwih, p.dwhh, p.dbih, p.dbhh, hc, ho, -1, nullptr,
              p.hbf, p.hn2 + (size_t)(s & 1) * 64);
    gbar(p.cnt);
    // 3b: bf16 MFMA logits + per-tile certified (lo,up) interval keys
    {
      u16* hA = (u16*)smem;            // [64][264] bf16, padded
      const int l15 = lane & 15, quad = lane >> 4;
      const int gw = wg * 8 + wv;      // 0..2047: this wave's first n-tile
      const bool two = (gw + 2048) < NTL;
      f4 acc0[4], acc1[4];
      #pragma unroll
      for (int m = 0; m < 4; m++) {
        #pragma unroll
        for (int r = 0; r < 4; r++) { acc0[m][r] = 0.f; acc1[m][r] = 0.f; }
      }
      for (int kp = 0; kp < 4; kp++) {          // K window: kp*256..+256
        for (int i = tid; i < 2048; i += TPB) {
          int r = i >> 5, c = i & 31;
          *(uint4*)(hA + r * 264 + c * 8) =
              *(const uint4*)(p.hbf + (size_t)r * HD + kp * 256 + c * 8);
        }
        __syncthreads();
        const u16* bp0 = p.owbf + (size_t)(gw * 16 + l15) * HD + kp * 256 + quad * 8;
        const u16* bp1 = bp0 + (size_t)2048 * 16 * HD;
        #pragma unroll
        for (int kc = 0; kc < 8; kc++) {
          int ko = kc * 32 + quad * 8;
          s8 b0 = *(const s8*)(bp0 + kc * 32);
          s8 a0 = *(const s8*)(hA + (0 * 16 + l15) * 264 + ko);
          s8 a1 = *(const s8*)(hA + (1 * 16 + l15) * 264 + ko);
          s8 a2 = *(const s8*)(hA + (2 * 16 + l15) * 264 + ko);
          s8 a3 = *(const s8*)(hA + (3 * 16 + l15) * 264 + ko);
          acc0[0] = __builtin_amdgcn_mfma_f32_16x16x32_bf16(a0, b0, acc0[0], 0, 0, 0);
          acc0[1] = __builtin_amdgcn_mfma_f32_16x16x32_bf16(a1, b0, acc0[1], 0, 0, 0);
          acc0[2] = __builtin_amdgcn_mfma_f32_16x16x32_bf16(a2, b0, acc0[2], 0, 0, 0);
          acc0[3] = __builtin_amdgcn_mfma_f32_16x16x32_bf16(a3, b0, acc0[3], 0, 0, 0);
          if (two) {
            s8 b1 = *(const s8*)(bp1 + kc * 32);
            acc1[0] = __builtin_amdgcn_mfma_f32_16x16x32_bf16(a0, b1, acc1[0], 0, 0, 0);
            acc1[1] = __builtin_amdgcn_mfma_f32_16x16x32_bf16(a1, b1, acc1[1], 0, 0, 0);
            acc1[2] = __builtin_amdgcn_mfma_f32_16x16x32_bf16(a2, b1, acc1[2], 0, 0, 0);
            acc1[3] = __builtin_amdgcn_mfma_f32_16x16x32_bf16(a3, b1, acc1[3], 0, 0, 0);
          }
        }
        __syncthreads();
      }
      // per-(batch,col) certified interval; reduce lo/up SEPARATELY over 16 cols
      float hroot[4][4];
      #pragma unroll
      for (int m = 0; m < 4; m++)
        #pragma unroll
        for (int r = 0; r < 4; r++)
          hroot[m][r] = sqrtf(p.hn2[(size_t)(s & 1) * 64 + m * 16 + quad * 4 + r]);
      auto epi = [&](int nt, f4* acc) {
        int col = nt * 16 + l15;
        float bias = p.outb[col];
        float wnc = p.wn[col];
        #pragma unroll
        for (int m = 0; m < 4; m++) {
          #pragma unroll
          for (int r = 0; r < 4; r++) {
            float v = acc[m][r] + bias;
            float e = 0.0082f * hroot[m][r] * wnc + 1e-5f;
            u32 klo = fkey(v - e), kup = fkey(v + e);
            #pragma unroll
            for (int d = 1; d < 16; d <<= 1) {
              u32 ol = __shfl_xor(klo, d); if (ol > klo) klo = ol;
              u32 ou = __shfl_xor(kup, d); if (ou > kup) kup = ou;
            }
            if (l15 == 0)
              p.prt[(size_t)nt * 64 + (m * 16 + quad * 4 + r)] =
                  ((u64)klo << 32) | kup;
          }
        }
      };
      epi(gw, acc0);
      if (two) epi(gw + 2048, acc1);
    }
    gbar(p.cnt);
    // 3c: threshold T = max lo; rescue every tile with up >= T in exact fp32
    if (wg < NB) {
      const int b = wg;
      float* hb = (float*)smem;                 // [1024] exact fp32 h
      u64* red = (u64*)(smem + 4096);           // [8]
      u64* gmp = (u64*)(smem + 4160);
      u64* bestp = (u64*)(smem + 4168);
      int* ncp = (int*)(smem + 4176);
      int* list = (int*)(smem + 4184);          // [LCAP]
      for (int i = tid; i < HD; i += TPB) hb[i] = ho[(size_t)i * NB + b];
      if (tid == 0) { *bestp = 0ull; *ncp = 0; }
      __syncthreads();
      u64 mx = 0;
      for (int nt = tid; nt < NTL; nt += TPB) {
        u64 v = p.prt[(size_t)nt * 64 + b];
        if (v > mx) mx = v;
      }
      #pragma unroll
      for (int d = 1; d < 64; d <<= 1) { u64 o = __shfl_xor(mx, d); if (o > mx) mx = o; }
      if (lane == 0) red[wv] = mx;
      __syncthreads();
      if (tid == 0) {
        u64 g = red[0];
        for (int w2 = 1; w2 < 8; w2++) if (red[w2] > g) g = red[w2];
        *gmp = g;
      }
      __syncthreads();
      const u32 thr = (u32)(*gmp >> 32);        // fkey(T), T = max over tiles of lo
      for (int nt = tid; nt < NTL; nt += TPB) {
        if ((u32)p.prt[(size_t)nt * 64 + b] >= thr) {   // up >= T
          int ix = atomicAdd(ncp, 1);
          if (ix < LCAP) list[ix] = nt;
        }
      }
      __syncthreads();
      int total = *ncp;
      int nc = total < LCAP ? total : LCAP;
      const int c16 = tid >> 5, seg = tid & 31;
      u64 lb = 0;
      auto rescue = [&](int nt) {
        int v = nt * 16 + c16;
        const float* wr = p.outw + (size_t)v * HD;
        float sm = 0.f;
        #pragma unroll 8
        for (int i = 0; i < 32; i++) {
          int k = seg + 32 * i;                 // bank-conflict-free, coalesced
          sm = fmaf(hb[k], wr[k], sm);
        }
        #pragma unroll
        for (int d = 1; d < 32; d <<= 1) sm += __shfl_xor(sm, d);
        if (seg == 0) {
          float lg = sm + p.outb[v];
          u64 k2 = ((u64)fkey(lg) << 32) | (~(u32)v);   // ~v: lowest idx wins ties
          if (k2 > lb) lb = k2;
        }
      };
      for (int ci = 0; ci < nc; ci++) rescue(list[ci]);
      if (total > LCAP) {                       // certified fallback (never expected)
        for (int nt = 0; nt < NTL; nt++)
          if ((u32)p.prt[(size_t)nt * 64 + b] >= thr) rescue(nt);
      }
      atomicMax((u64*)bestp, lb);
      __syncthreads();
      if (tid == 0) {
        u32 v = ~(u32)(*bestp);
        p.tok[b] = (int)v;
        p.out[b * DEC + s] = (float)v;
        p.hn2[(size_t)((s + 1) & 1) * 64 + b] = 0.f;    // reset slot for next step
      }
    }
    gbar(p.cnt);
  }
}

__global__ void seq2seq_init(u32* cnt, float* hn2, float* hTf, float* hTb) {
  int g = blockIdx.x * blockDim.x + threadIdx.x;
  if (g == 0) *cnt = 0;
  if (g < 128) hn2[g] = 0.f;
  int n = 2 * HEN * NB;
  for (int i = g; i < n; i += gridDim.x * blockDim.x) { hTf[i] = 0.f; hTb[i] = 0.f; }
}

extern "C" void kernel_launch(void* const* d_in, const int* in_sizes, int n_in,
                              void* d_out, int out_size, void* d_ws, size_t ws_size,
                              hipStream_t stream) {
  char* w = (char*)d_ws;
  size_t off = 0;
  auto carve = [&](size_t n) {
    void* q = w + off;
    off = (off + n + 255) & ~(size_t)255;
    return q;
  };
  P p;
  p.texts = (const int*)d_in[0];
  p.len   = (const int*)d_in[1];
  p.emb   = (const float*)d_in[2];
  p.ewih0 = (const float*)d_in[3];  p.ewhh0 = (const float*)d_in[4];
  p.ebih0 = (const float*)d_in[5];  p.ebhh0 = (const float*)d_in[6];
  p.ewih1 = (const float*)d_in[7];  p.ewhh1 = (const float*)d_in[8];
  p.ebih1 = (const float*)d_in[9];  p.ebhh1 = (const float*)d_in[10];
  p.dwih  = (const float*)d_in[11]; p.dwhh  = (const float*)d_in[12];
  p.dbih  = (const float*)d_in[13]; p.dbhh  = (const float*)d_in[14];
  p.outw  = (const float*)d_in[15]; p.outb  = (const float*)d_in[16];
  p.out   = (float*)d_out;
  p.owbf = (u16*)carve((size_t)VV * HD * 2);
  p.xT   = (float*)carve((size_t)TT * EE * NB * 4);
  p.hTf  = (float*)carve((size_t)2 * HEN * NB * 4);
  p.hTb  = (float*)carve((size_t)2 * HEN * NB * 4);
  p.hTd  = (float*)carve((size_t)2 * HD * NB * 4);
  p.hbf  = (u16*)carve((size_t)NB * HD * 2);
  p.prt  = (u64*)carve((size_t)NTL * 64 * 8);
  p.tok  = (int*)carve(256);
  p.wn   = (float*)carve((size_t)VV * 4);
  p.hn2  = (float*)carve(128 * 4);
  p.cnt  = (u32*)carve(256);
  if (off > ws_size) return;  // workspace too small: fail visibly

  hipLaunchKernelGGL(seq2seq_init, dim3(64), dim3(256), 0, stream,
                     p.cnt, p.hn2, p.hTf, p.hTb);
  void* args[] = { &p };
  hipError_t e = hipLaunchCooperativeKernel((void*)seq2seq_kernel,
                                            dim3(NWG), dim3(TPB), args, 0, stream);
  if (e != hipSuccess) {
    // fallback: plain launch (grid == CU count; co-resident de facto)
    seq2seq_kernel<<<dim3(NWG), dim3(TPB), 0, stream>>>(p);
  }
}

// Round 3
// 24430.865 us; speedup vs baseline: 1.3977x; 1.3977x over previous
//
#include <hip/hip_runtime.h>
#include <stdint.h>

typedef unsigned int u32;
typedef unsigned long long u64;
typedef unsigned short u16;
typedef __attribute__((ext_vector_type(8))) short s8;
typedef __attribute__((ext_vector_type(4))) float f4;

#define NWG 256
#define TPB 512
#define NB 64      // batch
#define TT 400     // seq len
#define EE 300     // embed dim
#define HEN 512    // encoder hidden
#define HD 1024    // decoder hidden
#define VV 50000   // vocab
#define DEC 80     // decode steps
#define NTL 3125   // VV/16 n-tiles
#define LCAP 512   // rescue list capacity
#define PBOFF 39168            // LDS: [0,PBOFF) weights/hA, [PBOFF,+16K) combine/merge
#define SMEMSZ (PBOFF + 16384)
#define RESC 0.00837f          // 2^-8 * 1.002 * 2.09 safety (bf16 h + bf16 w + fp32 acc)

struct P {
  const int* texts; const int* len; const float* emb;
  const float* ewih0; const float* ewhh0; const float* ebih0; const float* ebhh0;
  const float* ewih1; const float* ewhh1; const float* ebih1; const float* ebhh1;
  const float* dwih; const float* dwhh; const float* dbih; const float* dbhh;
  const float* outw; const float* outb;
  float* out;
  u16* owbf; float* xT; float* hTf; float* hTb; float* hTd; u16* hbf;
  u64* prt; int* tok; float* wn;
  u32* bgrp; u32* broot; u32* bepoch;
};

// Two-level tree barrier: 16 groups x 16 wgs, monotone epochs.
// HIP __syncthreads drains vmcnt before s_barrier, so all wg stores are in L2
// before tid0's release fence (wbl2) flushes them to fabric.
__device__ __forceinline__ void gbar(const P& p, u32& eb) {
  const u32 e = eb++;
  __syncthreads();
  if (threadIdx.x == 0) {
    __builtin_amdgcn_fence(__ATOMIC_RELEASE, "agent");
    u32* gc = p.bgrp + ((blockIdx.x >> 4) << 6);   // 256B-strided counter lines
    u32 old = __hip_atomic_fetch_add(gc, 1u, __ATOMIC_RELAXED, __HIP_MEMORY_SCOPE_AGENT);
    if (old == e * 16u + 15u) {                    // last of my group
      u32 r = __hip_atomic_fetch_add(p.broot, 1u, __ATOMIC_RELAXED, __HIP_MEMORY_SCOPE_AGENT);
      if (r == e * 16u + 15u)                      // last group overall
        __hip_atomic_store(p.bepoch, e + 1u, __ATOMIC_RELAXED, __HIP_MEMORY_SCOPE_AGENT);
    }
    while (__hip_atomic_load(p.bepoch, __ATOMIC_RELAXED, __HIP_MEMORY_SCOPE_AGENT) < e + 1u)
      __builtin_amdgcn_s_sleep(2);
    __builtin_amdgcn_fence(__ATOMIC_ACQUIRE, "agent");
  }
  __syncthreads();
}

__device__ __forceinline__ u32 fkey(float v) {
  u32 u = __float_as_uint(v);
  return (u & 0x80000000u) ? ~u : (u | 0x80000000u);
}
__device__ __forceinline__ u16 f2bf(float f) {   // RNE fp32->bf16
  u32 u = __float_as_uint(f);
  u32 r = u + 0x7FFFu + ((u >> 16) & 1u);
  return (u16)(r >> 16);
}
__device__ __forceinline__ float sigm(float x) { return 1.f / (1.f + expf(-x)); }

// ---- shared GRU epilogue: two-stage partial combine in 16KB LDS + activations
__device__ __forceinline__ void gru_combine_epi(
    char* smem, const f4& ar, const f4& az, const f4& ax, const f4& ah,
    int jjb, int HL, const float* bih, const float* bhh,
    const float* hc, float* ho, int mask_t, const int* lenp, u16* hbf_out)
{
  const int tid = threadIdx.x, lane = tid & 63, wv = tid >> 6;
  float* pb = (float*)(smem + PBOFF);     // [4][16][64]
  const int wl = wv & 3;
  if (wv < 4) {
    #pragma unroll
    for (int j = 0; j < 4; j++) {
      pb[((wl * 16 + j * 4 + 0) * 64) + lane] = ar[j];
      pb[((wl * 16 + j * 4 + 1) * 64) + lane] = az[j];
      pb[((wl * 16 + j * 4 + 2) * 64) + lane] = ax[j];
      pb[((wl * 16 + j * 4 + 3) * 64) + lane] = ah[j];
    }
  }
  __syncthreads();
  if (wv >= 4) {
    #pragma unroll
    for (int j = 0; j < 4; j++) {
      pb[((wl * 16 + j * 4 + 0) * 64) + lane] += ar[j];
      pb[((wl * 16 + j * 4 + 1) * 64) + lane] += az[j];
      pb[((wl * 16 + j * 4 + 2) * 64) + lane] += ax[j];
      pb[((wl * 16 + j * 4 + 3) * 64) + lane] += ah[j];
    }
  }
  __syncthreads();
  if (tid < 256) {
    int b = tid & 63, j = tid >> 6;
    int jj = jjb + j;
    float r = 0, z = 0, xn = 0, hn = 0;
    #pragma unroll
    for (int w = 0; w < 4; w++) {
      int base = ((w * 16 + j * 4) * 64) + b;
      r  += pb[base];
      z  += pb[base + 64];
      xn += pb[base + 128];
      hn += pb[base + 192];
    }
    r = sigm(r + bih[jj] + bhh[jj]);
    z = sigm(z + bih[HL + jj] + bhh[HL + jj]);
    float nn = tanhf(xn + bih[2 * HL + jj] + r * (hn + bhh[2 * HL + jj]));
    float hold = hc[(size_t)jj * NB + b];
    float hv = (1.f - z) * nn + z * hold;
    if (lenp && mask_t >= lenp[b]) hv = hold;
    ho[(size_t)jj * NB + b] = hv;
    if (hbf_out) hbf_out[(size_t)b * HD + jj] = f2bf(hv);
  }
}

// Encoder step: weights pre-staged in LDS [k][12] (gate-major within 48B row)
__device__ __forceinline__ void gru_enc(
    char* smem, int jjb, const float* xsrc,
    const float* bih, const float* bhh,
    const float* __restrict__ hc, float* ho, int tt, const int* lenp)
{
  const int tid = threadIdx.x, lane = tid & 63, wv = tid >> 6;
  const float* lw = (const float*)smem;
  const int KT = EE + HEN;
  const int vs = (wv * KT) >> 3, ve = ((wv + 1) * KT) >> 3;
  f4 ar = {0,0,0,0}, az = {0,0,0,0}, ax = {0,0,0,0}, ah = {0,0,0,0};
  int xe = ve < EE ? ve : EE;
  #pragma unroll 2
  for (int k = vs; k < xe; k++) {
    float xv = xsrc[(size_t)k * NB + lane];
    f4 w0 = *(const f4*)(lw + k * 12);
    f4 w1 = *(const f4*)(lw + k * 12 + 4);
    f4 w2 = *(const f4*)(lw + k * 12 + 8);
    ar += xv * w0; az += xv * w1; ax += xv * w2;
  }
  int hs = vs > EE ? vs : EE;
  #pragma unroll 2
  for (int k = hs; k < ve; k++) {
    float hv = hc[(size_t)(k - EE) * NB + lane];
    f4 w0 = *(const f4*)(lw + k * 12);
    f4 w1 = *(const f4*)(lw + k * 12 + 4);
    f4 w2 = *(const f4*)(lw + k * 12 + 8);
    ar += hv * w0; az += hv * w1; ah += hv * w2;
  }
  gru_combine_epi(smem, ar, az, ax, ah, jjb, HEN, bih, bhh, hc, ho, tt, lenp, nullptr);
}

// Decoder step: weights from global (80 steps only), x = emb[tok]
__device__ __forceinline__ void gru_dec(
    const P& p, char* smem, int jjb,
    const float* __restrict__ hc, float* ho)
{
  const int tid = threadIdx.x, lane = tid & 63, wv = tid >> 6;
  const float* wih = p.dwih; const float* whh = p.dwhh;
  const int KT = EE + HD;
  const int vs = (wv * KT) >> 3, ve = ((wv + 1) * KT) >> 3;
  f4 ar = {0,0,0,0}, az = {0,0,0,0}, ax = {0,0,0,0}, ah = {0,0,0,0};
  int xe = ve < EE ? ve : EE;
  if (vs < EE) {
    const float* xr = p.emb + (size_t)p.tok[lane] * EE;
    for (int k = vs; k < xe; k++) {
      float xv = xr[k];
      #pragma unroll
      for (int j = 0; j < 4; j++) {
        int jj = jjb + j;
        ar[j] = fmaf(xv, wih[(size_t)jj * EE + k], ar[j]);
        az[j] = fmaf(xv, wih[(size_t)(HD + jj) * EE + k], az[j]);
        ax[j] = fmaf(xv, wih[(size_t)(2 * HD + jj) * EE + k], ax[j]);
      }
    }
  }
  int hs = vs - EE; if (hs < 0) hs = 0;
  int he = ve - EE;
  for (int k = hs; k < he; k++) {
    float hv = hc[(size_t)k * NB + lane];
    #pragma unroll
    for (int j = 0; j < 4; j++) {
      int jj = jjb + j;
      ar[j] = fmaf(hv, whh[(size_t)jj * HD + k], ar[j]);
      az[j] = fmaf(hv, whh[(size_t)(HD + jj) * HD + k], az[j]);
      ah[j] = fmaf(hv, whh[(size_t)(2 * HD + jj) * HD + k], ah[j]);
    }
  }
  gru_combine_epi(smem, ar, az, ax, ah, jjb, HD, p.dbih, p.dbhh,
                  hc, ho, -1, nullptr, p.hbf);
}

__global__ void __launch_bounds__(TPB, 2) seq2seq_kernel(P p) {
  __shared__ __align__(16) char smem[SMEMSZ];
  const int wg = blockIdx.x, tid = threadIdx.x;
  const int lane = tid & 63, wv = tid >> 6;
  const int gtid = wg * TPB + tid;
  u32 eb = 0;

  const int dir = wg >> 7;           // encoder: wgs 0..127 fwd, 128..255 bwd
  const int ejjb = (wg & 127) * 4;

  // ---------------- phase 0: one-time prep ----------------
  {
    // stage this wg's encoder weight slice into LDS: lw[k][g*4+j]
    const float* wih = dir ? p.ewih1 : p.ewih0;
    const float* whh = dir ? p.ewhh1 : p.ewhh0;
    float* lw = (float*)smem;
    for (int c = wv; c < 12; c += 8) {
      int g = c >> 2, j = c & 3;
      const float* sx = wih + (size_t)(g * HEN + ejjb + j) * EE;
      for (int k = lane; k < EE; k += 64) lw[k * 12 + c] = sx[k];
      const float* sh = whh + (size_t)(g * HEN + ejjb + j) * HEN;
      for (int k = lane; k < HEN; k += 64) lw[(EE + k) * 12 + c] = sh[k];
    }
    // out_w -> bf16 copy + per-row L2 norm (certified rescue bound)
    int gwv = wg * 8 + wv;
    for (int v = gwv; v < VV; v += 2048) {
      const float* wr = p.outw + (size_t)v * HD + lane * 16;
      u16* dst = p.owbf + (size_t)v * HD + lane * 16;
      float sa = 0.f;
      u32 pk[8];
      #pragma unroll
      for (int q = 0; q < 4; q++) {
        float4 f = *(const float4*)(wr + q * 4);
        sa += f.x * f.x + f.y * f.y + f.z * f.z + f.w * f.w;
        pk[q * 2 + 0] = (u32)f2bf(f.x) | ((u32)f2bf(f.y) << 16);
        pk[q * 2 + 1] = (u32)f2bf(f.z) | ((u32)f2bf(f.w) << 16);
      }
      *(uint4*)(dst)     = make_uint4(pk[0], pk[1], pk[2], pk[3]);
      *(uint4*)(dst + 8) = make_uint4(pk[4], pk[5], pk[6], pk[7]);
      #pragma unroll
      for (int d = 1; d < 64; d <<= 1) sa += __shfl_xor(sa, d);
      if (lane == 0) p.wn[v] = sqrtf(sa);
    }
    // gather+transpose encoder inputs: xT[t][k][b] = emb[texts[b][t]][k]
    const long long tot = (long long)TT * NB * EE;
    for (long long i = gtid; i < tot; i += (long long)NWG * TPB) {
      int t = (int)(i / (NB * EE));
      int rr = (int)(i % (NB * EE));
      int b2 = rr / EE, k = rr % EE;
      float v = p.emb[(size_t)p.texts[b2 * TT + t] * EE + k];
      p.xT[((size_t)t * EE + k) * NB + b2] = v;
    }
  }
  gbar(p, eb);

  // ---------------- phase 1: bidirectional encoder ----------------
  {
    const float* bih = dir ? p.ebih1 : p.ebih0;
    const float* bhh = dir ? p.ebhh1 : p.ebhh0;
    float* hbase = dir ? p.hTb : p.hTf;
    for (int t = 0; t < TT; t++) {
      int te = dir ? (TT - 1 - t) : t;
      const float* hc = hbase + (size_t)(t & 1) * HEN * NB;
      float* ho = hbase + (size_t)((t + 1) & 1) * HEN * NB;
      gru_enc(smem, ejjb, p.xT + (size_t)te * EE * NB, bih, bhh, hc, ho, te, p.len);
      gbar(p, eb);
    }
  }

  // ---------------- phase 2: concat hidden, init tok ----------------
  {
    for (int i = gtid; i < HD * NB; i += NWG * TPB) {
      int k = i / NB, b2 = i % NB;
      float v = (k < HEN) ? p.hTf[(size_t)k * NB + b2] : p.hTb[(size_t)(k - HEN) * NB + b2];
      p.hTd[i] = v;
    }
    if (gtid < NB) p.tok[gtid] = 1;   // sos
  }
  gbar(p, eb);

  // ---------------- phase 3: decoder ----------------
  for (int s = 0; s < DEC; s++) {
    const float* hc = p.hTd + (size_t)(s & 1) * HD * NB;
    float* ho = p.hTd + (size_t)((s + 1) & 1) * HD * NB;
    // 3a: GRU step (emits bf16 row-major h)
    gru_dec(p, smem, wg * 4, hc, ho);
    gbar(p, eb);
    // 3b: bf16 MFMA logits + per-tile certified (lo,up) interval keys.
    // ||h_b||^2 computed for free during hA staging (LDS atomics).
    {
      u16* hA = (u16*)smem;                 // [64][264] bf16, padded
      float* hsq = (float*)(smem + PBOFF);  // [64]
      const int l15 = lane & 15, quad = lane >> 4;
      const int gw = wg * 8 + wv;
      const bool two = (gw + 2048) < NTL;
      if (tid < 64) hsq[tid] = 0.f;
      __syncthreads();
      f4 acc0[4], acc1[4];
      #pragma unroll
      for (int m = 0; m < 4; m++) {
        #pragma unroll
        for (int r = 0; r < 4; r++) { acc0[m][r] = 0.f; acc1[m][r] = 0.f; }
      }
      for (int kp = 0; kp < 4; kp++) {          // K window: kp*256..+256
        for (int i = tid; i < 2048; i += TPB) {
          int r = i >> 5, c = i & 31;
          uint4 q = *(const uint4*)(p.hbf + (size_t)r * HD + kp * 256 + c * 8);
          *(uint4*)(hA + r * 264 + c * 8) = q;
          u32 uu[4] = {q.x, q.y, q.z, q.w};
          float sq = 0.f;
          #pragma unroll
          for (int t2 = 0; t2 < 4; t2++) {
            float lo = __uint_as_float(uu[t2] << 16);
            float hi = __uint_as_float(uu[t2] & 0xffff0000u);
            sq = fmaf(lo, lo, fmaf(hi, hi, sq));
          }
          atomicAdd(&hsq[r], sq);
        }
        __syncthreads();
        const u16* bp0 = p.owbf + (size_t)(gw * 16 + l15) * HD + kp * 256 + quad * 8;
        const u16* bp1 = bp0 + (size_t)2048 * 16 * HD;
        #pragma unroll
        for (int kc = 0; kc < 8; kc++) {
          int ko = kc * 32 + quad * 8;
          s8 b0 = *(const s8*)(bp0 + kc * 32);
          s8 a0 = *(const s8*)(hA + (0 * 16 + l15) * 264 + ko);
          s8 a1 = *(const s8*)(hA + (1 * 16 + l15) * 264 + ko);
          s8 a2 = *(const s8*)(hA + (2 * 16 + l15) * 264 + ko);
          s8 a3 = *(const s8*)(hA + (3 * 16 + l15) * 264 + ko);
          acc0[0] = __builtin_amdgcn_mfma_f32_16x16x32_bf16(a0, b0, acc0[0], 0, 0, 0);
          acc0[1] = __builtin_amdgcn_mfma_f32_16x16x32_bf16(a1, b0, acc0[1], 0, 0, 0);
          acc0[2] = __builtin_amdgcn_mfma_f32_16x16x32_bf16(a2, b0, acc0[2], 0, 0, 0);
          acc0[3] = __builtin_amdgcn_mfma_f32_16x16x32_bf16(a3, b0, acc0[3], 0, 0, 0);
          if (two) {
            s8 b1 = *(const s8*)(bp1 + kc * 32);
            acc1[0] = __builtin_amdgcn_mfma_f32_16x16x32_bf16(a0, b1, acc1[0], 0, 0, 0);
            acc1[1] = __builtin_amdgcn_mfma_f32_16x16x32_bf16(a1, b1, acc1[1], 0, 0, 0);
            acc1[2] = __builtin_amdgcn_mfma_f32_16x16x32_bf16(a2, b1, acc1[2], 0, 0, 0);
            acc1[3] = __builtin_amdgcn_mfma_f32_16x16x32_bf16(a3, b1, acc1[3], 0, 0, 0);
          }
        }
        __syncthreads();
      }
      float hroot[4][4];
      #pragma unroll
      for (int m = 0; m < 4; m++)
        #pragma unroll
        for (int r = 0; r < 4; r++)
          hroot[m][r] = sqrtf(hsq[m * 16 + quad * 4 + r]);
      auto epi = [&](int nt, f4* acc) {
        int col = nt * 16 + l15;
        float bias = p.outb[col];
        float wnc = p.wn[col];
        #pragma unroll
        for (int m = 0; m < 4; m++) {
          #pragma unroll
          for (int r = 0; r < 4; r++) {
            float v = acc[m][r] + bias;
            float e = RESC * hroot[m][r] * wnc + 1e-5f;
            u32 klo = fkey(v - e), kup = fkey(v + e);
            #pragma unroll
            for (int d = 1; d < 16; d <<= 1) {
              u32 ol = __shfl_xor(klo, d); if (ol > klo) klo = ol;
              u32 ou = __shfl_xor(kup, d); if (ou > kup) kup = ou;
            }
            if (l15 == 0)
              p.prt[(size_t)nt * 64 + (m * 16 + quad * 4 + r)] =
                  ((u64)klo << 32) | kup;
          }
        }
      };
      epi(gw, acc0);
      if (two) epi(gw + 2048, acc1);
    }
    gbar(p, eb);
    // 3c: threshold T = max lo; rescue every tile with up >= T in exact fp32
    if (wg < NB) {
      const int b = wg;
      char* ms = smem + PBOFF;
      float* hb = (float*)ms;                   // [1024] exact fp32 h
      u64* red = (u64*)(ms + 4096);             // [8]
      u64* gmp = (u64*)(ms + 4160);
      u64* bestp = (u64*)(ms + 4168);
      int* ncp = (int*)(ms + 4176);
      int* list = (int*)(ms + 4192);            // [LCAP]
      for (int i = tid; i < HD; i += TPB) hb[i] = ho[(size_t)i * NB + b];
      if (tid == 0) { *bestp = 0ull; *ncp = 0; }
      __syncthreads();
      u64 mx = 0;
      for (int nt = tid; nt < NTL; nt += TPB) {
        u64 v = p.prt[(size_t)nt * 64 + b];
        if (v > mx) mx = v;
      }
      #pragma unroll
      for (int d = 1; d < 64; d <<= 1) { u64 o = __shfl_xor(mx, d); if (o > mx) mx = o; }
      if (lane == 0) red[wv] = mx;
      __syncthreads();
      if (tid == 0) {
        u64 g = red[0];
        for (int w2 = 1; w2 < 8; w2++) if (red[w2] > g) g = red[w2];
        *gmp = g;
      }
      __syncthreads();
      const u32 thr = (u32)(*gmp >> 32);        // fkey(T), T = max of lo
      for (int nt = tid; nt < NTL; nt += TPB) {
        if ((u32)p.prt[(size_t)nt * 64 + b] >= thr) {   // up >= T
          int ix = atomicAdd(ncp, 1);
          if (ix < LCAP) list[ix] = nt;
        }
      }
      __syncthreads();
      int total = *ncp;
      int nc = total < LCAP ? total : LCAP;
      const int c16 = tid >> 5, seg = tid & 31;
      u64 lb = 0;
      auto rescue = [&](int nt) {
        int v = nt * 16 + c16;
        const float* wr = p.outw + (size_t)v * HD;
        float sm = 0.f;
        #pragma unroll 8
        for (int i = 0; i < 32; i++) {
          int k = seg + 32 * i;
          sm = fmaf(hb[k], wr[k], sm);
        }
        #pragma unroll
        for (int d = 1; d < 32; d <<= 1) sm += __shfl_xor(sm, d);
        if (seg == 0) {
          float lg = sm + p.outb[v];
          u64 k2 = ((u64)fkey(lg) << 32) | (~(u32)v);   // ~v: lowest idx wins ties
          if (k2 > lb) lb = k2;
        }
      };
      for (int ci = 0; ci < nc; ci++) rescue(list[ci]);
      if (total > LCAP) {                       // certified fallback
        for (int nt = 0; nt < NTL; nt++)
          if ((u32)p.prt[(size_t)nt * 64 + b] >= thr) rescue(nt);
      }
      if (seg == 0 && lb) atomicMax((unsigned long long*)bestp, lb);
      __syncthreads();
      if (tid == 0) {
        u32 v = ~(u32)(*bestp);
        p.tok[b] = (int)v;
        p.out[b * DEC + s] = (float)v;
      }
    }
    gbar(p, eb);
  }
}

__global__ void seq2seq_init(u32* bgrp, u32* broot, u32* bepoch,
                             float* hTf, float* hTb) {
  int g = blockIdx.x * blockDim.x + threadIdx.x;
  if (g < 1024) bgrp[g] = 0u;
  if (g == 0) { *broot = 0u; *bepoch = 0u; }
  int n = 2 * HEN * NB;
  for (int i = g; i < n; i += gridDim.x * blockDim.x) { hTf[i] = 0.f; hTb[i] = 0.f; }
}

extern "C" void kernel_launch(void* const* d_in, const int* in_sizes, int n_in,
                              void* d_out, int out_size, void* d_ws, size_t ws_size,
                              hipStream_t stream) {
  char* w = (char*)d_ws;
  size_t off = 0;
  auto carve = [&](size_t n) {
    void* q = w + off;
    off = (off + n + 255) & ~(size_t)255;
    return q;
  };
  P p;
  p.texts = (const int*)d_in[0];
  p.len   = (const int*)d_in[1];
  p.emb   = (const float*)d_in[2];
  p.ewih0 = (const float*)d_in[3];  p.ewhh0 = (const float*)d_in[4];
  p.ebih0 = (const float*)d_in[5];  p.ebhh0 = (const float*)d_in[6];
  p.ewih1 = (const float*)d_in[7];  p.ewhh1 = (const float*)d_in[8];
  p.ebih1 = (const float*)d_in[9];  p.ebhh1 = (const float*)d_in[10];
  p.dwih  = (const float*)d_in[11]; p.dwhh  = (const float*)d_in[12];
  p.dbih  = (const float*)d_in[13]; p.dbhh  = (const float*)d_in[14];
  p.outw  = (const float*)d_in[15]; p.outb  = (const float*)d_in[16];
  p.out   = (float*)d_out;
  p.owbf  = (u16*)carve((size_t)VV * HD * 2);
  p.xT    = (float*)carve((size_t)TT * EE * NB * 4);
  p.hTf   = (float*)carve((size_t)2 * HEN * NB * 4);
  p.hTb   = (float*)carve((size_t)2 * HEN * NB * 4);
  p.hTd   = (float*)carve((size_t)2 * HD * NB * 4);
  p.hbf   = (u16*)carve((size_t)NB * HD * 2);
  p.prt   = (u64*)carve((size_t)NTL * 64 * 8);
  p.tok   = (int*)carve(256);
  p.wn    = (float*)carve((size_t)VV * 4);
  p.bgrp  = (u32*)carve(1024 * 4);
  p.broot = (u32*)carve(256);
  p.bepoch= (u32*)carve(256);
  if (off > ws_size) return;  // workspace too small: fail visibly

  hipLaunchKernelGGL(seq2seq_init, dim3(64), dim3(256), 0, stream,
                     p.bgrp, p.broot, p.bepoch, p.hTf, p.hTb);
  void* args[] = { &p };
  hipError_t e = hipLaunchCooperativeKernel((void*)seq2seq_kernel,
                                            dim3(NWG), dim3(TPB), args, 0, stream);
  if (e != hipSuccess) {
    seq2seq_kernel<<<dim3(NWG), dim3(TPB), 0, stream>>>(p);
  }
}